// Round 12
// baseline (1199.303 us; speedup 1.0000x reference)
//
#include <hip/hip_runtime.h>

// CrossLayerTranscoder. R12: occupancy-2 deep pipeline.
//  - dec8/enc8: BK=32, packed-2-rows LDS layout (128B phys rows, R3-verified),
//    3 x 24KB buffers = 72KB -> 2 blocks/CU (4 waves/SIMD TLP), depth-2
//    prefetch, counted vmcnt(3), raw barriers, setprio MFMA clusters.
//  - dec8 grid: 512 blocks heavy-first (lp=7-f>>6); finish-time backfill
//    pairs heavy+light per CU.
//  - enc8 grid: 3072 blocks; every 3rd converts 1/1024 of Wd (co-resident
//    with GEMM blocks at 2/CU -> true BW/MFMA overlap).
//  - conv1: res/We f32->bf16 (288 MB).

#define MT 2048   // B*S
#define HD 1024   // H
#define FD 4096   // F
#define LL 8      // L

typedef __attribute__((ext_vector_type(8))) short short8;
typedef __attribute__((ext_vector_type(4))) float f32x4;
typedef __attribute__((ext_vector_type(4))) unsigned short ushort4v;

typedef const __attribute__((address_space(1))) void GV;
typedef __attribute__((address_space(3))) void LV;

__device__ __forceinline__ void gload16(const void* g, void* l) {
  __builtin_amdgcn_global_load_lds((GV*)g, (LV*)l, 16, 0, 0);
}

#define BAR()                                  \
  do {                                         \
    __builtin_amdgcn_sched_barrier(0);         \
    __builtin_amdgcn_s_barrier();              \
    __builtin_amdgcn_sched_barrier(0);         \
  } while (0)

__device__ __forceinline__ unsigned int f2bf1(float x) {
  unsigned u = __float_as_uint(x);
  return (u + 0x7FFFu + ((u >> 16) & 1u)) >> 16;   // RNE f32->bf16
}

// ======================= fallback-path helpers (R2) ========================
__device__ __forceinline__ void load_tile(const float* __restrict__ base, int ld,
                                          float4* r) {
  const int t = threadIdx.x;
#pragma unroll
  for (int i = 0; i < 8; ++i) {
    int idx = t + 256 * i;
    int row = idx >> 4;
    int c4  = idx & 15;
    r[i] = *(const float4*)(base + (size_t)row * ld + c4 * 4);
  }
}

__device__ __forceinline__ void write_tile(char* lds, const float4* r) {
  const int t = threadIdx.x;
#pragma unroll
  for (int i = 0; i < 8; ++i) {
    int idx = t + 256 * i;
    int row = idx >> 4;
    int c4  = idx & 15;
    int off = (row * 128 + c4 * 8) ^ ((row & 7) << 4);
    unsigned lo = f2bf1(r[i].x) | (f2bf1(r[i].y) << 16);
    unsigned hi = f2bf1(r[i].z) | (f2bf1(r[i].w) << 16);
    *(uint2*)(lds + off) = make_uint2(lo, hi);
  }
}

__device__ __forceinline__ void load_tile_bf(const unsigned short* __restrict__ base,
                                             int ld, short8* r) {
  const int t = threadIdx.x;
#pragma unroll
  for (int i = 0; i < 4; ++i) {
    int idx = t + 256 * i;
    int row = idx >> 3;
    int c8  = idx & 7;
    r[i] = *(const short8*)(base + (size_t)row * ld + c8 * 8);
  }
}

__device__ __forceinline__ void write_tile_bf(char* lds, const short8* r) {
  const int t = threadIdx.x;
#pragma unroll
  for (int i = 0; i < 4; ++i) {
    int idx = t + 256 * i;
    int row = idx >> 3;
    int c8  = idx & 7;
    int off = (row * 128 + c8 * 16) ^ ((row & 7) << 4);
    *(short8*)(lds + off) = r[i];
  }
}

__device__ __forceinline__ void compute_tile(const char* sA, const char* sB,
                                             f32x4 acc[4][4], int wr, int wc,
                                             int l16, int h16) {
#pragma unroll
  for (int ks = 0; ks < 2; ++ks) {
    short8 a[4], b[4];
#pragma unroll
    for (int i = 0; i < 4; ++i) {
      int row = wr * 64 + i * 16 + l16;
      a[i] = *(const short8*)(sA + ((row * 128 + ks * 64 + h16 * 16) ^ ((row & 7) << 4)));
    }
#pragma unroll
    for (int j = 0; j < 4; ++j) {
      int col = wc * 64 + j * 16 + l16;
      b[j] = *(const short8*)(sB + ((col * 128 + ks * 64 + h16 * 16) ^ ((col & 7) << 4)));
    }
#pragma unroll
    for (int i = 0; i < 4; ++i)
#pragma unroll
      for (int j = 0; j < 4; ++j)
        acc[i][j] = __builtin_amdgcn_mfma_f32_16x16x32_bf16(a[i], b[j], acc[i][j], 0, 0, 0);
  }
}

// ---------------- conv1: res/We f32 -> bf16 (BW-bound) ---------------------
__global__ __launch_bounds__(256) void conv1(
    const float* __restrict__ res, const float* __restrict__ We,
    unsigned short* __restrict__ res_bf, unsigned short* __restrict__ we_bf) {
  const size_t stride = (size_t)gridDim.x * 256;
  const size_t i0 = (size_t)blockIdx.x * 256 + threadIdx.x;
  auto cv = [&](const float* __restrict__ s, unsigned short* __restrict__ d,
                size_t n4) {
    const float4* s4 = (const float4*)s;
    for (size_t k = i0; k < n4; k += stride) {
      float4 v = s4[k];
      ushort4v o;
      o.x = (unsigned short)f2bf1(v.x);
      o.y = (unsigned short)f2bf1(v.y);
      o.z = (unsigned short)f2bf1(v.z);
      o.w = (unsigned short)f2bf1(v.w);
      *(ushort4v*)(d + k * 4) = o;
    }
  };
  cv(res, res_bf, (size_t)LL * MT * HD / 4);
  cv(We,  we_bf,  (size_t)LL * FD * HD / 4);
}

// ======================= BK=32 deep-pipeline common ========================
// LDS buffer: A 128 phys rows x 128B (16KB) + B 64 phys rows x 128B (8KB).
// Packed layout: logical row m, k-slot k (16B) -> phys p=m>>1,
// slot s = (((m&1)<<2)|k) ^ (p&7).  gload_lds dest is linear (t*16);
// source pre-swizzled via sl=(t&7)^((t>>3)&7), mloc=2*(t>>3)+(sl>>2),
// koff=(sl&3)*8.  [layout HW-verified in R3]
#define DBUF 24576

// ---------------- dec8: 512 blocks heavy-first, 2 blocks/CU ----------------
__global__ __launch_bounds__(512, 4) void dec8(
    const unsigned short* __restrict__ featsbf,
    const unsigned short* __restrict__ wdbf,
    const float* __restrict__ bd, float* __restrict__ recon) {
  __shared__ char lds[3 * DBUF];   // 72 KB -> 2 blocks/CU

  const int f = (int)blockIdx.x;       // 0..511
  const int lp = 7 - (f >> 6);         // heavy first; backfill pairs to 9 units
  const int g = f & 63;
  const int m0 = (g >> 3) * 256;
  const int h0 = (g & 7) * 128;

  const int t = threadIdx.x;           // 0..511
  const int L = t & 63, w = t >> 6;
  const int wm = w >> 1, wn = w & 1;   // 4M x 2N waves, 64x64 each
  const int l16 = L & 15, h16 = L >> 4;

  const int sl   = (t & 7) ^ ((t >> 3) & 7);
  const int mloc = 2 * (t >> 3) + (sl >> 2);       // 0..127
  const int koff = (sl & 3) * 8;
  const size_t laneA = (size_t)(m0 + mloc) * FD + koff;
  const size_t laneB = (size_t)(h0 + mloc) * FD + koff;

  const int NT = (lp + 1) * 128;       // BK=32 steps

  f32x4 acc[4][4];
#pragma unroll
  for (int i = 0; i < 4; ++i)
#pragma unroll
    for (int j = 0; j < 4; ++j) acc[i][j] = (f32x4){0.f, 0.f, 0.f, 0.f};

  auto stage = [&](int bi, int tt) {
    int l = tt >> 7, kt = tt & 127;
    int p = l * LL - ((l * (l - 1)) >> 1) + (lp - l);
    const unsigned short* Ab = featsbf + (size_t)l * MT * FD + kt * 32 + laneA;
    const unsigned short* Bb = wdbf + (size_t)p * HD * FD + kt * 32 + laneB;
    char* dA = lds + bi * DBUF + t * 16;
    gload16(Ab, dA);
    gload16(Ab + (size_t)128 * FD, dA + 8192);
    gload16(Bb, dA + 16384);
  };

  auto rfrag = [&](int bi, short8* a, short8* b) {
    const char* cA = lds + bi * DBUF;
    const char* cB = cA + 16384;
#pragma unroll
    for (int i = 0; i < 4; ++i) {
      int m = wm * 64 + i * 16 + l16;
      int p = m >> 1;
      int s = (((m & 1) << 2) | h16) ^ (p & 7);
      a[i] = *(const short8*)(cA + p * 128 + s * 16);
    }
#pragma unroll
    for (int j = 0; j < 4; ++j) {
      int c = wn * 64 + j * 16 + l16;
      int p = c >> 1;
      int s = (((c & 1) << 2) | h16) ^ (p & 7);
      b[j] = *(const short8*)(cB + p * 128 + s * 16);
    }
  };

  auto cluster = [&](const short8* a, const short8* b) {
    __builtin_amdgcn_s_setprio(1);
#pragma unroll
    for (int i = 0; i < 4; ++i)
#pragma unroll
      for (int j = 0; j < 4; ++j)
        acc[i][j] = __builtin_amdgcn_mfma_f32_16x16x32_bf16(a[i], b[j], acc[i][j], 0, 0, 0);
    __builtin_amdgcn_s_setprio(0);
  };

  stage(0, 0);
  stage(1, 1);
  asm volatile("s_waitcnt vmcnt(3)" ::: "memory");
  BAR();

  short8 aC[4], bC[4];
  rfrag(0, aC, bC);

  int rd = 0;
  for (int tt = 0; tt < NT; ++tt) {
    int st = rd + 2;
    if (st >= 3) st -= 3;
    if (tt + 2 < NT) stage(st, tt + 2);   // loads span this step + next
    cluster(aC, bC);
    if (tt + 2 < NT) {
      asm volatile("s_waitcnt vmcnt(3)" ::: "memory");   // tile tt+1 landed
    } else if (tt + 1 < NT) {
      asm volatile("s_waitcnt vmcnt(0)" ::: "memory");   // drain tail
    }
    BAR();
    int nrd = (rd + 1 == 3) ? 0 : rd + 1;
    if (tt + 1 < NT) rfrag(nrd, aC, bC);  // covered by co-resident waves (TLP)
    rd = nrd;
  }

#pragma unroll
  for (int j = 0; j < 4; ++j) {
    int col = h0 + wn * 64 + j * 16 + l16;
    float bsum = 0.f;
    for (int l = 0; l <= lp; ++l) {
      int p = l * LL - ((l * (l - 1)) >> 1) + (lp - l);
      bsum += bd[(size_t)p * HD + col];
    }
#pragma unroll
    for (int i = 0; i < 4; ++i) {
      int rbase = m0 + wm * 64 + i * 16 + h16 * 4;
#pragma unroll
      for (int q = 0; q < 4; ++q)
        recon[((size_t)lp * MT + rbase + q) * HD + col] = acc[i][j][q] + bsum;
    }
  }
}

// ---------------- enc8: same skeleton + Wd-conv role blocks ----------------
// Grid 3072: flat%3==2 -> conv 1/1024 of Wd; else enc GEMM (eid 0..2047).
__global__ __launch_bounds__(512, 4) void enc8(
    const unsigned short* __restrict__ resbf,
    const unsigned short* __restrict__ webf,
    const float* __restrict__ be, const float* __restrict__ thresh,
    float* __restrict__ feats, unsigned short* __restrict__ feats_bf,
    const float* __restrict__ wd_src, unsigned short* __restrict__ wd_dst) {
  __shared__ char lds[3 * DBUF];

  const int flat = (int)blockIdx.x;
  const int r3 = flat % 3;
  if (r3 == 2) {
    // conv role: 1024 blocks x 36864 float4 (72/thread @512 thr) = all of Wd.
    const int cid = flat / 3;
    const float4* src = (const float4*)wd_src;
    size_t base = (size_t)cid * 36864 + threadIdx.x;
#pragma unroll 4
    for (int i = 0; i < 72; ++i) {
      size_t k = base + (size_t)i * 512;
      float4 v = src[k];
      ushort4v o;
      o.x = (unsigned short)f2bf1(v.x);
      o.y = (unsigned short)f2bf1(v.y);
      o.z = (unsigned short)f2bf1(v.z);
      o.w = (unsigned short)f2bf1(v.w);
      *(ushort4v*)(wd_dst + k * 4) = o;
    }
    return;
  }

  const int eid = (flat / 3) * 2 + r3;         // 0..2047
  const int nf = (eid & 7) * 256 + (eid >> 3); // XCD x = layer x
  const int bx = nf & 31;
  const int by = (nf >> 5) & 7;
  const int l  = nf >> 8;

  const int m0 = by * 256;
  const int f0 = bx * 128;

  const int t = threadIdx.x;
  const int L = t & 63, w = t >> 6;
  const int wm = w >> 1, wn = w & 1;
  const int l16 = L & 15, h16 = L >> 4;

  const int sl   = (t & 7) ^ ((t >> 3) & 7);
  const int mloc = 2 * (t >> 3) + (sl >> 2);
  const int koff = (sl & 3) * 8;
  const unsigned short* Abase = resbf + (size_t)l * MT * HD;
  const unsigned short* Bbase = webf + (size_t)l * FD * HD;
  const size_t laneA = (size_t)(m0 + mloc) * HD + koff;
  const size_t laneB = (size_t)(f0 + mloc) * HD + koff;

  const int NT = HD / 32;              // 32

  f32x4 acc[4][4];
#pragma unroll
  for (int i = 0; i < 4; ++i)
#pragma unroll
    for (int j = 0; j < 4; ++j) acc[i][j] = (f32x4){0.f, 0.f, 0.f, 0.f};

  auto stage = [&](int bi, int tt) {
    const unsigned short* Ab = Abase + (size_t)tt * 32 + laneA;
    const unsigned short* Bb = Bbase + (size_t)tt * 32 + laneB;
    char* dA = lds + bi * DBUF + t * 16;
    gload16(Ab, dA);
    gload16(Ab + (size_t)128 * HD, dA + 8192);
    gload16(Bb, dA + 16384);
  };

  auto rfrag = [&](int bi, short8* a, short8* b) {
    const char* cA = lds + bi * DBUF;
    const char* cB = cA + 16384;
#pragma unroll
    for (int i = 0; i < 4; ++i) {
      int m = wm * 64 + i * 16 + l16;
      int p = m >> 1;
      int s = (((m & 1) << 2) | h16) ^ (p & 7);
      a[i] = *(const short8*)(cA + p * 128 + s * 16);
    }
#pragma unroll
    for (int j = 0; j < 4; ++j) {
      int c = wn * 64 + j * 16 + l16;
      int p = c >> 1;
      int s = (((c & 1) << 2) | h16) ^ (p & 7);
      b[j] = *(const short8*)(cB + p * 128 + s * 16);
    }
  };

  auto cluster = [&](const short8* a, const short8* b) {
    __builtin_amdgcn_s_setprio(1);
#pragma unroll
    for (int i = 0; i < 4; ++i)
#pragma unroll
      for (int j = 0; j < 4; ++j)
        acc[i][j] = __builtin_amdgcn_mfma_f32_16x16x32_bf16(a[i], b[j], acc[i][j], 0, 0, 0);
    __builtin_amdgcn_s_setprio(0);
  };

  stage(0, 0);
  stage(1, 1);
  asm volatile("s_waitcnt vmcnt(3)" ::: "memory");
  BAR();

  short8 aC[4], bC[4];
  rfrag(0, aC, bC);

  int rd = 0;
  for (int tt = 0; tt < NT; ++tt) {
    int st = rd + 2;
    if (st >= 3) st -= 3;
    if (tt + 2 < NT) stage(st, tt + 2);
    cluster(aC, bC);
    if (tt + 2 < NT) {
      asm volatile("s_waitcnt vmcnt(3)" ::: "memory");
    } else if (tt + 1 < NT) {
      asm volatile("s_waitcnt vmcnt(0)" ::: "memory");
    }
    BAR();
    int nrd = (rd + 1 == 3) ? 0 : rd + 1;
    if (tt + 1 < NT) rfrag(nrd, aC, bC);
    rd = nrd;
  }

  const float th = thresh[l];
#pragma unroll
  for (int j = 0; j < 4; ++j) {
    int col = f0 + wn * 64 + j * 16 + l16;
    float bev = be[(size_t)l * FD + col];
#pragma unroll
    for (int i = 0; i < 4; ++i) {
      int rbase = m0 + wm * 64 + i * 16 + h16 * 4;
#pragma unroll
      for (int q = 0; q < 4; ++q) {
        float v = acc[i][j][q] + bev;
        float g = (v > th) ? v : 0.f;
        size_t idx = ((size_t)l * MT + rbase + q) * FD + col;
        feats[idx] = g;
        feats_bf[idx] = (unsigned short)f2bf1(g);
      }
    }
  }
}

// ======================= fallback kernels (R2 path) ========================
__global__ __launch_bounds__(256, 2) void enc_kernel(
    const float* __restrict__ res, const float* __restrict__ We,
    const float* __restrict__ be, const float* __restrict__ thresh,
    float* __restrict__ feats, unsigned short* __restrict__ feats_bf) {
  __shared__ char sA[128 * 64 * 2];
  __shared__ char sB[128 * 64 * 2];

  const int l  = blockIdx.z;
  const int m0 = blockIdx.y * 128;
  const int f0 = blockIdx.x * 128;

  const float* Abase = res + (size_t)l * MT * HD + (size_t)m0 * HD;
  const float* Bbase = We  + (size_t)l * FD * HD + (size_t)f0 * HD;

  const int t = threadIdx.x;
  const int lane = t & 63, wave = t >> 6;
  const int wr = wave >> 1, wc = wave & 1;
  const int l16 = lane & 15, h16 = lane >> 4;

  f32x4 acc[4][4];
#pragma unroll
  for (int i = 0; i < 4; ++i)
#pragma unroll
    for (int j = 0; j < 4; ++j) acc[i][j] = (f32x4){0.f, 0.f, 0.f, 0.f};

  float4 ra[8], rb[8];
  load_tile(Abase, HD, ra);
  load_tile(Bbase, HD, rb);

  const int NK = HD / 64;
  for (int kt = 0; kt < NK; ++kt) {
    write_tile(sA, ra);
    write_tile(sB, rb);
    __syncthreads();
    if (kt + 1 < NK) {
      load_tile(Abase + (kt + 1) * 64, HD, ra);
      load_tile(Bbase + (kt + 1) * 64, HD, rb);
    }
    compute_tile(sA, sB, acc, wr, wc, l16, h16);
    __syncthreads();
  }

  const float th = thresh[l];
#pragma unroll
  for (int j = 0; j < 4; ++j) {
    int col = f0 + wc * 64 + j * 16 + l16;
    float bev = be[(size_t)l * FD + col];
#pragma unroll
    for (int i = 0; i < 4; ++i) {
      int rbase = m0 + wr * 64 + i * 16 + h16 * 4;
#pragma unroll
      for (int q = 0; q < 4; ++q) {
        float v = acc[i][j][q] + bev;
        float g = (v > th) ? v : 0.f;
        size_t idx = ((size_t)l * MT + rbase + q) * FD + col;
        feats[idx] = g;
        if (feats_bf) feats_bf[idx] = (unsigned short)f2bf1(g);
      }
    }
  }
}

template <bool ABF16>
__global__ __launch_bounds__(256, 2) void dec_kernel(
    const float* __restrict__ feats_f32, const unsigned short* __restrict__ feats_bf,
    const float* __restrict__ Wd, const float* __restrict__ bd,
    float* __restrict__ recon) {
  __shared__ char sA[128 * 64 * 2];
  __shared__ char sB[128 * 64 * 2];

  const int lp = (LL - 1) - (int)blockIdx.z;
  const int m0 = blockIdx.y * 128;
  const int h0 = blockIdx.x * 128;

  const int t = threadIdx.x;
  const int lane = t & 63, wave = t >> 6;
  const int wr = wave >> 1, wc = wave & 1;
  const int l16 = lane & 15, h16 = lane >> 4;

  f32x4 acc[4][4];
#pragma unroll
  for (int i = 0; i < 4; ++i)
#pragma unroll
    for (int j = 0; j < 4; ++j) acc[i][j] = (f32x4){0.f, 0.f, 0.f, 0.f};

  const int nit = (lp + 1) * (FD / 64);

  auto Abf = [&](int it) -> const unsigned short* {
    int l = it >> 6, kt = it & 63;
    return feats_bf + ((size_t)l * MT + m0) * FD + kt * 64;
  };
  auto Af = [&](int it) -> const float* {
    int l = it >> 6, kt = it & 63;
    return feats_f32 + ((size_t)l * MT + m0) * FD + kt * 64;
  };
  auto Bb = [&](int it) -> const float* {
    int l = it >> 6, kt = it & 63;
    int p = l * LL - l * (l - 1) / 2 + (lp - l);
    return Wd + ((size_t)p * HD + h0) * FD + kt * 64;
  };

  short8 rab[4];
  float4 raf[8];
  float4 rb[8];
  if constexpr (ABF16) load_tile_bf(Abf(0), FD, rab); else load_tile(Af(0), FD, raf);
  load_tile(Bb(0), FD, rb);

  for (int it = 0; it < nit; ++it) {
    if constexpr (ABF16) write_tile_bf(sA, rab); else write_tile(sA, raf);
    write_tile(sB, rb);
    __syncthreads();
    if (it + 1 < nit) {
      if constexpr (ABF16) load_tile_bf(Abf(it + 1), FD, rab);
      else                 load_tile(Af(it + 1), FD, raf);
      load_tile(Bb(it + 1), FD, rb);
    }
    compute_tile(sA, sB, acc, wr, wc, l16, h16);
    __syncthreads();
  }

#pragma unroll
  for (int j = 0; j < 4; ++j) {
    int col = h0 + wc * 64 + j * 16 + l16;
    float bsum = 0.f;
    for (int l = 0; l <= lp; ++l) {
      int p = l * LL - l * (l - 1) / 2 + (lp - l);
      bsum += bd[(size_t)p * HD + col];
    }
#pragma unroll
    for (int i = 0; i < 4; ++i) {
      int rbase = m0 + wr * 64 + i * 16 + h16 * 4;
#pragma unroll
      for (int q = 0; q < 4; ++q) {
        recon[((size_t)lp * MT + rbase + q) * HD + col] = acc[i][j][q] + bsum;
      }
    }
  }
}

extern "C" void kernel_launch(void* const* d_in, const int* in_sizes, int n_in,
                              void* d_out, int out_size, void* d_ws, size_t ws_size,
                              hipStream_t stream) {
  const float* res    = (const float*)d_in[0];
  const float* We     = (const float*)d_in[1];
  const float* be     = (const float*)d_in[2];
  const float* Wd     = (const float*)d_in[3];
  const float* bd     = (const float*)d_in[4];
  const float* thresh = (const float*)d_in[5];

  float* recon = (float*)d_out;                       // L*M*H
  float* feats = recon + (size_t)LL * MT * HD;        // L*M*F

  const size_t featsbf_b = (size_t)LL * MT * FD * 2;  // 128 MiB
  const size_t wdbf_b    = (size_t)36 * HD * FD * 2;  // 288 MiB
  const size_t resbf_b   = (size_t)LL * MT * HD * 2;  //  32 MiB
  const size_t webf_b    = (size_t)LL * FD * HD * 2;  //  64 MiB

  const bool use_bf = ws_size >= featsbf_b;
  const bool use_v3 = ws_size >= featsbf_b + wdbf_b + resbf_b + webf_b; // 512 MiB

  unsigned short* feats_bf = (unsigned short*)d_ws;
  unsigned short* wd_bf    = (unsigned short*)((char*)d_ws + featsbf_b);
  unsigned short* res_bf   = (unsigned short*)((char*)d_ws + featsbf_b + wdbf_b);
  unsigned short* we_bf    = (unsigned short*)((char*)d_ws + featsbf_b + wdbf_b + resbf_b);

  if (use_v3) {
    conv1<<<dim3(1024), dim3(256), 0, stream>>>(res, We, res_bf, we_bf);
    enc8<<<dim3(3072), dim3(512), 0, stream>>>(res_bf, we_bf, be, thresh,
                                               feats, feats_bf, Wd, wd_bf);
    dec8<<<dim3(512), dim3(512), 0, stream>>>(feats_bf, wd_bf, bd, recon);
  } else if (use_bf) {
    enc_kernel<<<dim3(32, 16, LL), dim3(256), 0, stream>>>(
        res, We, be, thresh, feats, feats_bf);
    dec_kernel<true><<<dim3(8, 16, LL), dim3(256), 0, stream>>>(
        feats, feats_bf, Wd, bd, recon);
  } else {
    enc_kernel<<<dim3(32, 16, LL), dim3(256), 0, stream>>>(
        res, We, be, thresh, feats, nullptr);
    dec_kernel<false><<<dim3(8, 16, LL), dim3(256), 0, stream>>>(
        feats, nullptr, Wd, bd, recon);
  }
}

// Round 13
// 1062.022 us; speedup vs baseline: 1.1293x; 1.1293x over previous
//
#include <hip/hip_runtime.h>

// CrossLayerTranscoder. R13 (best-known components only):
//  - enc_f32: R2-proven reg-staged f32 encoder (128x128, BK=64, 2 blocks/CU),
//    dual-writes feats f32 + feats_bf. No input conversion needed.
//  - convWd: standalone Wd f32->bf16 (906 MB traffic).
//  - dec8: R10 byte-identical deep-pipeline decoder (BK=64, paired lp,
//    3x48KB bufs, gload_lds pre-swizzled, depth-2, vmcnt(6), R9 frag pipe).

#define MT 2048   // B*S
#define HD 1024   // H
#define FD 4096   // F
#define LL 8      // L

typedef __attribute__((ext_vector_type(8))) short short8;
typedef __attribute__((ext_vector_type(4))) float f32x4;
typedef __attribute__((ext_vector_type(4))) unsigned short ushort4v;

typedef const __attribute__((address_space(1))) void GV;
typedef __attribute__((address_space(3))) void LV;

__device__ __forceinline__ void gload16(const void* g, void* l) {
  __builtin_amdgcn_global_load_lds((GV*)g, (LV*)l, 16, 0, 0);
}

#define BAR()                                  \
  do {                                         \
    __builtin_amdgcn_sched_barrier(0);         \
    __builtin_amdgcn_s_barrier();              \
    __builtin_amdgcn_sched_barrier(0);         \
  } while (0)

__device__ __forceinline__ unsigned int f2bf1(float x) {
  unsigned u = __float_as_uint(x);
  return (u + 0x7FFFu + ((u >> 16) & 1u)) >> 16;   // RNE f32->bf16
}

// ---- f32 tile staging (128x64, row stride ld), reg-staged (encoder) -------
__device__ __forceinline__ void load_tile(const float* __restrict__ base, int ld,
                                          float4* r) {
  const int t = threadIdx.x;
#pragma unroll
  for (int i = 0; i < 8; ++i) {
    int idx = t + 256 * i;
    int row = idx >> 4;
    int c4  = idx & 15;
    r[i] = *(const float4*)(base + (size_t)row * ld + c4 * 4);
  }
}

__device__ __forceinline__ void write_tile(char* lds, const float4* r) {
  const int t = threadIdx.x;
#pragma unroll
  for (int i = 0; i < 8; ++i) {
    int idx = t + 256 * i;
    int row = idx >> 4;
    int c4  = idx & 15;
    int off = (row * 128 + c4 * 8) ^ ((row & 7) << 4);
    unsigned lo = f2bf1(r[i].x) | (f2bf1(r[i].y) << 16);
    unsigned hi = f2bf1(r[i].z) | (f2bf1(r[i].w) << 16);
    *(uint2*)(lds + off) = make_uint2(lo, hi);
  }
}

// ---- bf16 tile staging (128x64) for fallback decoder ----------------------
__device__ __forceinline__ void load_tile_bf(const unsigned short* __restrict__ base,
                                             int ld, short8* r) {
  const int t = threadIdx.x;
#pragma unroll
  for (int i = 0; i < 4; ++i) {
    int idx = t + 256 * i;
    int row = idx >> 3;
    int c8  = idx & 7;
    r[i] = *(const short8*)(base + (size_t)row * ld + c8 * 8);
  }
}

__device__ __forceinline__ void write_tile_bf(char* lds, const short8* r) {
  const int t = threadIdx.x;
#pragma unroll
  for (int i = 0; i < 4; ++i) {
    int idx = t + 256 * i;
    int row = idx >> 3;
    int c8  = idx & 7;
    int off = (row * 128 + c8 * 16) ^ ((row & 7) << 4);
    *(short8*)(lds + off) = r[i];
  }
}

// One BK=64 step (encoder/fallback): 2 x (read frags + 16 MFMA).
__device__ __forceinline__ void compute_tile(const char* sA, const char* sB,
                                             f32x4 acc[4][4], int wr, int wc,
                                             int l16, int h16) {
#pragma unroll
  for (int ks = 0; ks < 2; ++ks) {
    short8 a[4], b[4];
#pragma unroll
    for (int i = 0; i < 4; ++i) {
      int row = wr * 64 + i * 16 + l16;
      a[i] = *(const short8*)(sA + ((row * 128 + ks * 64 + h16 * 16) ^ ((row & 7) << 4)));
    }
#pragma unroll
    for (int j = 0; j < 4; ++j) {
      int col = wc * 64 + j * 16 + l16;
      b[j] = *(const short8*)(sB + ((col * 128 + ks * 64 + h16 * 16) ^ ((col & 7) << 4)));
    }
#pragma unroll
    for (int i = 0; i < 4; ++i)
#pragma unroll
      for (int j = 0; j < 4; ++j)
        acc[i][j] = __builtin_amdgcn_mfma_f32_16x16x32_bf16(a[i], b[j], acc[i][j], 0, 0, 0);
  }
}

// ---------------- convWd: Wd f32 -> bf16 (906 MB, BW-bound) ----------------
__global__ __launch_bounds__(256) void convWd(
    const float* __restrict__ Wd, unsigned short* __restrict__ wd_bf) {
  const size_t stride = (size_t)gridDim.x * 256;
  const size_t n4 = (size_t)36 * HD * FD / 4;   // 37,748,736 float4
  const float4* s4 = (const float4*)Wd;
  for (size_t k = (size_t)blockIdx.x * 256 + threadIdx.x; k < n4; k += stride) {
    float4 v = s4[k];
    ushort4v o;
    o.x = (unsigned short)f2bf1(v.x);
    o.y = (unsigned short)f2bf1(v.y);
    o.z = (unsigned short)f2bf1(v.z);
    o.w = (unsigned short)f2bf1(v.w);
    *(ushort4v*)(wd_bf + k * 4) = o;
  }
}

// ---------------- enc_f32: R2-proven reg-staged f32 encoder ----------------
__global__ __launch_bounds__(256, 2) void enc_f32(
    const float* __restrict__ res, const float* __restrict__ We,
    const float* __restrict__ be, const float* __restrict__ thresh,
    float* __restrict__ feats, unsigned short* __restrict__ feats_bf) {
  __shared__ char sA[128 * 64 * 2];
  __shared__ char sB[128 * 64 * 2];

  const int l  = blockIdx.z;
  const int m0 = blockIdx.y * 128;
  const int f0 = blockIdx.x * 128;

  const float* Abase = res + (size_t)l * MT * HD + (size_t)m0 * HD;
  const float* Bbase = We  + (size_t)l * FD * HD + (size_t)f0 * HD;

  const int t = threadIdx.x;
  const int lane = t & 63, wave = t >> 6;
  const int wr = wave >> 1, wc = wave & 1;
  const int l16 = lane & 15, h16 = lane >> 4;

  f32x4 acc[4][4];
#pragma unroll
  for (int i = 0; i < 4; ++i)
#pragma unroll
    for (int j = 0; j < 4; ++j) acc[i][j] = (f32x4){0.f, 0.f, 0.f, 0.f};

  float4 ra[8], rb[8];
  load_tile(Abase, HD, ra);
  load_tile(Bbase, HD, rb);

  const int NK = HD / 64;
  for (int kt = 0; kt < NK; ++kt) {
    write_tile(sA, ra);
    write_tile(sB, rb);
    __syncthreads();
    if (kt + 1 < NK) {
      load_tile(Abase + (kt + 1) * 64, HD, ra);
      load_tile(Bbase + (kt + 1) * 64, HD, rb);
    }
    compute_tile(sA, sB, acc, wr, wc, l16, h16);
    __syncthreads();
  }

  const float th = thresh[l];
#pragma unroll
  for (int j = 0; j < 4; ++j) {
    int col = f0 + wc * 64 + j * 16 + l16;
    float bev = be[(size_t)l * FD + col];
#pragma unroll
    for (int i = 0; i < 4; ++i) {
      int rbase = m0 + wr * 64 + i * 16 + h16 * 4;
#pragma unroll
      for (int q = 0; q < 4; ++q) {
        float v = acc[i][j][q] + bev;
        float g = (v > th) ? v : 0.f;
        size_t idx = ((size_t)l * MT + rbase + q) * FD + col;
        feats[idx] = g;
        if (feats_bf) feats_bf[idx] = (unsigned short)f2bf1(g);
      }
    }
  }
}

// ---------------- dec8: R10 deep pipeline + frag software pipeline ---------
// LDS per buffer: A 256x64 bf16 (32 KB) + B 128x64 bf16 (16 KB) = 48 KB.
// 3 buffers, depth-2 prefetch. LDS[row][s] = G[row][s ^ (row&7)] via
// pre-swizzled global source slot (linear gload_lds dest).
#define DEC_ABUF 32768
#define DEC_BUFSZ 49152
__global__ __launch_bounds__(512, 2) void dec8(
    const unsigned short* __restrict__ featsbf,
    const unsigned short* __restrict__ wdbf,
    const float* __restrict__ bd, float* __restrict__ recon) {
  __shared__ char lds[3 * DEC_BUFSZ];   // 144 KB -> 1 block/CU

  // XCD-chunk swizzle over 256 blocks (8 XCDs x 32-block chunks, bijective).
  const int flat = (int)(blockIdx.x + 8 * blockIdx.y + 64 * blockIdx.z);
  const int nf = (flat & 7) * 32 + (flat >> 3);
  const int bx = nf & 7;          // h-tile
  const int by = (nf >> 3) & 7;   // m-tile
  const int z  = nf >> 6;         // 0..3 -> lp pair (7-z, z)

  const int m0 = by * 256;
  const int h0 = bx * 128;

  const int t = threadIdx.x;          // 0..511
  const int L = t & 63;
  const int w = t >> 6;               // 8 waves
  const int wm = w >> 1, wn = w & 1;  // 4M x 2N
  const int l16 = L & 15, h16 = L >> 4;

  const int rl   = (t >> 3) & 7;
  const int scol = (t & 7) ^ rl;            // pre-swizzled source 16B-slot
  const int rowl = t >> 3;                  // 0..63
  const size_t laneA = (size_t)(m0 + rowl) * FD + scol * 8;
  const size_t laneB = (size_t)(h0 + rowl) * FD + scol * 8;

  const int s0 = h16 ^ (l16 & 7);

  for (int sub = 0; sub < 2; ++sub) {
    const int lp = sub ? z : 7 - z;
    const int NT = (lp + 1) * 64;

    f32x4 acc[4][4];
#pragma unroll
    for (int i = 0; i < 4; ++i)
#pragma unroll
      for (int j = 0; j < 4; ++j) acc[i][j] = (f32x4){0.f, 0.f, 0.f, 0.f};

    auto stage = [&](int bi, int tt) {
      int l = tt >> 6, kt = tt & 63;
      int p = l * LL - ((l * (l - 1)) >> 1) + (lp - l);
      const unsigned short* Ab = featsbf + (size_t)l * MT * FD + kt * 64 + laneA;
      const unsigned short* Bb = wdbf + (size_t)p * HD * FD + kt * 64 + laneB;
      char* dA = lds + bi * DEC_BUFSZ + t * 16;
      char* dB = dA + DEC_ABUF;
#pragma unroll
      for (int i = 0; i < 4; ++i)
        gload16(Ab + (size_t)i * 64 * FD, dA + i * 8192);
#pragma unroll
      for (int i = 0; i < 2; ++i)
        gload16(Bb + (size_t)i * 64 * FD, dB + i * 8192);
    };

    auto rfrag = [&](int bi, int ks, short8* a, short8* b) {
      const char* cA = lds + bi * DEC_BUFSZ;
      const char* cB = cA + DEC_ABUF;
      const int sl = (s0 ^ (ks << 2)) << 4;
#pragma unroll
      for (int i = 0; i < 4; ++i) {
        int row = wm * 64 + i * 16 + l16;
        a[i] = *(const short8*)(cA + row * 128 + sl);
      }
#pragma unroll
      for (int j = 0; j < 4; ++j) {
        int col = wn * 64 + j * 16 + l16;
        b[j] = *(const short8*)(cB + col * 128 + sl);
      }
    };

    auto cluster = [&](const short8* a, const short8* b) {
      __builtin_amdgcn_s_setprio(1);
#pragma unroll
      for (int i = 0; i < 4; ++i)
#pragma unroll
        for (int j = 0; j < 4; ++j)
          acc[i][j] = __builtin_amdgcn_mfma_f32_16x16x32_bf16(a[i], b[j], acc[i][j], 0, 0, 0);
      __builtin_amdgcn_s_setprio(0);
    };

    stage(0, 0);
    stage(1, 1);
    asm volatile("s_waitcnt vmcnt(6)" ::: "memory");
    BAR();

    short8 aC[4], bC[4], aN[4], bN[4];
    rfrag(0, 0, aC, bC);

    int rd = 0;
    for (int tt = 0; tt < NT; ++tt) {
      int st = rd + 2;
      if (st >= 3) st -= 3;
      if (tt + 2 < NT) stage(st, tt + 2);
      rfrag(rd, 1, aN, bN);
      cluster(aC, bC);
      if (tt + 2 < NT) {
        asm volatile("s_waitcnt vmcnt(6)" ::: "memory");
      } else if (tt + 1 < NT) {
        asm volatile("s_waitcnt vmcnt(0)" ::: "memory");
      }
      BAR();
      int nrd = (rd + 1 == 3) ? 0 : rd + 1;
      if (tt + 1 < NT) rfrag(nrd, 0, aC, bC);
      cluster(aN, bN);
      rd = nrd;
    }

#pragma unroll
    for (int j = 0; j < 4; ++j) {
      int col = h0 + wn * 64 + j * 16 + l16;
      float bsum = 0.f;
      for (int l = 0; l <= lp; ++l) {
        int p = l * LL - ((l * (l - 1)) >> 1) + (lp - l);
        bsum += bd[(size_t)p * HD + col];
      }
#pragma unroll
      for (int i = 0; i < 4; ++i) {
        int rbase = m0 + wm * 64 + i * 16 + h16 * 4;
#pragma unroll
        for (int q = 0; q < 4; ++q)
          recon[((size_t)lp * MT + rbase + q) * HD + col] = acc[i][j][q] + bsum;
      }
    }
  }
}

// ---------------- Fallback decoder (R2 2-phase, reg-staged) ----------------
template <bool ABF16>
__global__ __launch_bounds__(256, 2) void dec_kernel(
    const float* __restrict__ feats_f32, const unsigned short* __restrict__ feats_bf,
    const float* __restrict__ Wd, const float* __restrict__ bd,
    float* __restrict__ recon) {
  __shared__ char sA[128 * 64 * 2];
  __shared__ char sB[128 * 64 * 2];

  const int lp = (LL - 1) - (int)blockIdx.z;
  const int m0 = blockIdx.y * 128;
  const int h0 = blockIdx.x * 128;

  const int t = threadIdx.x;
  const int lane = t & 63, wave = t >> 6;
  const int wr = wave >> 1, wc = wave & 1;
  const int l16 = lane & 15, h16 = lane >> 4;

  f32x4 acc[4][4];
#pragma unroll
  for (int i = 0; i < 4; ++i)
#pragma unroll
    for (int j = 0; j < 4; ++j) acc[i][j] = (f32x4){0.f, 0.f, 0.f, 0.f};

  const int nit = (lp + 1) * (FD / 64);

  auto Abf = [&](int it) -> const unsigned short* {
    int l = it >> 6, kt = it & 63;
    return feats_bf + ((size_t)l * MT + m0) * FD + kt * 64;
  };
  auto Af = [&](int it) -> const float* {
    int l = it >> 6, kt = it & 63;
    return feats_f32 + ((size_t)l * MT + m0) * FD + kt * 64;
  };
  auto Bb = [&](int it) -> const float* {
    int l = it >> 6, kt = it & 63;
    int p = l * LL - l * (l - 1) / 2 + (lp - l);
    return Wd + ((size_t)p * HD + h0) * FD + kt * 64;
  };

  short8 rab[4];
  float4 raf[8];
  float4 rb[8];
  if constexpr (ABF16) load_tile_bf(Abf(0), FD, rab); else load_tile(Af(0), FD, raf);
  load_tile(Bb(0), FD, rb);

  for (int it = 0; it < nit; ++it) {
    if constexpr (ABF16) write_tile_bf(sA, rab); else write_tile(sA, raf);
    write_tile(sB, rb);
    __syncthreads();
    if (it + 1 < nit) {
      if constexpr (ABF16) load_tile_bf(Abf(it + 1), FD, rab);
      else                 load_tile(Af(it + 1), FD, raf);
      load_tile(Bb(it + 1), FD, rb);
    }
    compute_tile(sA, sB, acc, wr, wc, l16, h16);
    __syncthreads();
  }

#pragma unroll
  for (int j = 0; j < 4; ++j) {
    int col = h0 + wc * 64 + j * 16 + l16;
    float bsum = 0.f;
    for (int l = 0; l <= lp; ++l) {
      int p = l * LL - l * (l - 1) / 2 + (lp - l);
      bsum += bd[(size_t)p * HD + col];
    }
#pragma unroll
    for (int i = 0; i < 4; ++i) {
      int rbase = m0 + wr * 64 + i * 16 + h16 * 4;
#pragma unroll
      for (int q = 0; q < 4; ++q) {
        recon[((size_t)lp * MT + rbase + q) * HD + col] = acc[i][j][q] + bsum;
      }
    }
  }
}

extern "C" void kernel_launch(void* const* d_in, const int* in_sizes, int n_in,
                              void* d_out, int out_size, void* d_ws, size_t ws_size,
                              hipStream_t stream) {
  const float* res    = (const float*)d_in[0];
  const float* We     = (const float*)d_in[1];
  const float* be     = (const float*)d_in[2];
  const float* Wd     = (const float*)d_in[3];
  const float* bd     = (const float*)d_in[4];
  const float* thresh = (const float*)d_in[5];

  float* recon = (float*)d_out;                       // L*M*H
  float* feats = recon + (size_t)LL * MT * HD;        // L*M*F

  const size_t featsbf_b = (size_t)LL * MT * FD * 2;  // 128 MiB
  const size_t wdbf_b    = (size_t)36 * HD * FD * 2;  // 288 MiB

  const bool use_bf   = ws_size >= featsbf_b;
  const bool use_full = ws_size >= featsbf_b + wdbf_b;   // 416 MiB

  unsigned short* feats_bf = (unsigned short*)d_ws;
  unsigned short* wd_bf    = (unsigned short*)((char*)d_ws + featsbf_b);

  if (use_full) {
    convWd<<<dim3(2048), dim3(256), 0, stream>>>(Wd, wd_bf);
    enc_f32<<<dim3(32, 16, LL), dim3(256), 0, stream>>>(
        res, We, be, thresh, feats, feats_bf);
    dec8<<<dim3(8, 8, 4), dim3(512), 0, stream>>>(feats_bf, wd_bf, bd, recon);
  } else if (use_bf) {
    enc_f32<<<dim3(32, 16, LL), dim3(256), 0, stream>>>(
        res, We, be, thresh, feats, feats_bf);
    dec_kernel<true><<<dim3(8, 16, LL), dim3(256), 0, stream>>>(
        feats, feats_bf, Wd, bd, recon);
  } else {
    enc_f32<<<dim3(32, 16, LL), dim3(256), 0, stream>>>(
        res, We, be, thresh, feats, nullptr);
    dec_kernel<false><<<dim3(8, 16, LL), dim3(256), 0, stream>>>(
        feats, nullptr, Wd, bd, recon);
  }
}

// Round 14
// 1002.272 us; speedup vs baseline: 1.1966x; 1.0596x over previous
//
#include <hip/hip_runtime.h>

// CrossLayerTranscoder. R14 = R10 byte-identical (best measured: 1003 us).
//  - conv_kernel: one BW-bound pass converting res/We/Wd to bf16 in ws.
//  - enc8: encoder GEMM on the dec8 deep-pipeline skeleton (gload_lds,
//    pre-swizzled source, 3 bufs, depth-2, vmcnt(6), R9 frag pipeline),
//    all-bf16 inputs, epilogue = bias+JumpReLU dual-write.
//    XCD swizzle maps layer l -> XCD l (res_bf[l]=4MB L2-resident).
//  - dec8: R9 deep-pipeline decoder (~590-640 us, MfmaUtil ~50).

#define MT 2048   // B*S
#define HD 1024   // H
#define FD 4096   // F
#define LL 8      // L

typedef __attribute__((ext_vector_type(8))) short short8;
typedef __attribute__((ext_vector_type(4))) float f32x4;
typedef __attribute__((ext_vector_type(4))) unsigned short ushort4v;

typedef const __attribute__((address_space(1))) void GV;
typedef __attribute__((address_space(3))) void LV;

__device__ __forceinline__ void gload16(const void* g, void* l) {
  __builtin_amdgcn_global_load_lds((GV*)g, (LV*)l, 16, 0, 0);
}

#define BAR()                                  \
  do {                                         \
    __builtin_amdgcn_sched_barrier(0);         \
    __builtin_amdgcn_s_barrier();              \
    __builtin_amdgcn_sched_barrier(0);         \
  } while (0)

__device__ __forceinline__ unsigned int f2bf1(float x) {
  unsigned u = __float_as_uint(x);
  return (u + 0x7FFFu + ((u >> 16) & 1u)) >> 16;   // RNE f32->bf16
}

// ---- f32 tile staging (128x64, row stride ld), reg-staged (old encoder) ---
__device__ __forceinline__ void load_tile(const float* __restrict__ base, int ld,
                                          float4* r) {
  const int t = threadIdx.x;
#pragma unroll
  for (int i = 0; i < 8; ++i) {
    int idx = t + 256 * i;
    int row = idx >> 4;
    int c4  = idx & 15;
    r[i] = *(const float4*)(base + (size_t)row * ld + c4 * 4);
  }
}

__device__ __forceinline__ void write_tile(char* lds, const float4* r) {
  const int t = threadIdx.x;
#pragma unroll
  for (int i = 0; i < 8; ++i) {
    int idx = t + 256 * i;
    int row = idx >> 4;
    int c4  = idx & 15;
    int off = (row * 128 + c4 * 8) ^ ((row & 7) << 4);
    unsigned lo = f2bf1(r[i].x) | (f2bf1(r[i].y) << 16);
    unsigned hi = f2bf1(r[i].z) | (f2bf1(r[i].w) << 16);
    *(uint2*)(lds + off) = make_uint2(lo, hi);
  }
}

// ---- bf16 tile staging (128x64) for fallback decoder ----------------------
__device__ __forceinline__ void load_tile_bf(const unsigned short* __restrict__ base,
                                             int ld, short8* r) {
  const int t = threadIdx.x;
#pragma unroll
  for (int i = 0; i < 4; ++i) {
    int idx = t + 256 * i;
    int row = idx >> 3;
    int c8  = idx & 7;
    r[i] = *(const short8*)(base + (size_t)row * ld + c8 * 8);
  }
}

__device__ __forceinline__ void write_tile_bf(char* lds, const short8* r) {
  const int t = threadIdx.x;
#pragma unroll
  for (int i = 0; i < 4; ++i) {
    int idx = t + 256 * i;
    int row = idx >> 3;
    int c8  = idx & 7;
    int off = (row * 128 + c8 * 16) ^ ((row & 7) << 4);
    *(short8*)(lds + off) = r[i];
  }
}

// One BK=64 step (old enc/fallback): 2 x (read frags + 16 MFMA).
__device__ __forceinline__ void compute_tile(const char* sA, const char* sB,
                                             f32x4 acc[4][4], int wr, int wc,
                                             int l16, int h16) {
#pragma unroll
  for (int ks = 0; ks < 2; ++ks) {
    short8 a[4], b[4];
#pragma unroll
    for (int i = 0; i < 4; ++i) {
      int row = wr * 64 + i * 16 + l16;
      a[i] = *(const short8*)(sA + ((row * 128 + ks * 64 + h16 * 16) ^ ((row & 7) << 4)));
    }
#pragma unroll
    for (int j = 0; j < 4; ++j) {
      int col = wc * 64 + j * 16 + l16;
      b[j] = *(const short8*)(sB + ((col * 128 + ks * 64 + h16 * 16) ^ ((col & 7) << 4)));
    }
#pragma unroll
    for (int i = 0; i < 4; ++i)
#pragma unroll
      for (int j = 0; j < 4; ++j)
        acc[i][j] = __builtin_amdgcn_mfma_f32_16x16x32_bf16(a[i], b[j], acc[i][j], 0, 0, 0);
  }
}

// ---------------- conv_kernel: res/We/Wd f32 -> bf16 (BW-bound) ------------
__global__ __launch_bounds__(256) void conv_kernel(
    const float* __restrict__ res, const float* __restrict__ We,
    const float* __restrict__ Wd, unsigned short* __restrict__ res_bf,
    unsigned short* __restrict__ we_bf, unsigned short* __restrict__ wd_bf) {
  const size_t stride = (size_t)gridDim.x * 256;
  const size_t i0 = (size_t)blockIdx.x * 256 + threadIdx.x;
  auto cv = [&](const float* __restrict__ s, unsigned short* __restrict__ d,
                size_t n4) {
    const float4* s4 = (const float4*)s;
    for (size_t k = i0; k < n4; k += stride) {
      float4 v = s4[k];
      ushort4v o;
      o.x = (unsigned short)f2bf1(v.x);
      o.y = (unsigned short)f2bf1(v.y);
      o.z = (unsigned short)f2bf1(v.z);
      o.w = (unsigned short)f2bf1(v.w);
      *(ushort4v*)(d + k * 4) = o;
    }
  };
  cv(res, res_bf, (size_t)LL * MT * HD / 4);
  cv(We,  we_bf,  (size_t)LL * FD * HD / 4);
  cv(Wd,  wd_bf,  (size_t)36 * HD * FD / 4);
}

// ---------------- Old encoder (fallback; + Wd-conversion z-slices) ---------
__global__ __launch_bounds__(256, 2) void enc_kernel(
    const float* __restrict__ res, const float* __restrict__ We,
    const float* __restrict__ be, const float* __restrict__ thresh,
    float* __restrict__ feats, unsigned short* __restrict__ feats_bf,
    const float* __restrict__ wd_src, unsigned short* __restrict__ wd_dst,
    int conv_z) {
  __shared__ char sA[128 * 64 * 2];
  __shared__ char sB[128 * 64 * 2];

  if ((int)blockIdx.z < conv_z) {
    size_t chunk = ((size_t)blockIdx.z * 16 + blockIdx.y) * 32 + blockIdx.x;
    size_t base = chunk * 36864 + threadIdx.x;
    const float4* src = (const float4*)wd_src;
#pragma unroll 4
    for (int i = 0; i < 144; ++i) {
      size_t k = base + (size_t)i * 256;
      float4 v = src[k];
      ushort4v o;
      o.x = (unsigned short)f2bf1(v.x);
      o.y = (unsigned short)f2bf1(v.y);
      o.z = (unsigned short)f2bf1(v.z);
      o.w = (unsigned short)f2bf1(v.w);
      *(ushort4v*)(wd_dst + k * 4) = o;
    }
    return;
  }

  const int l  = blockIdx.z - conv_z;
  const int m0 = blockIdx.y * 128;
  const int f0 = blockIdx.x * 128;

  const float* Abase = res + (size_t)l * MT * HD + (size_t)m0 * HD;
  const float* Bbase = We  + (size_t)l * FD * HD + (size_t)f0 * HD;

  const int t = threadIdx.x;
  const int lane = t & 63, wave = t >> 6;
  const int wr = wave >> 1, wc = wave & 1;
  const int l16 = lane & 15, h16 = lane >> 4;

  f32x4 acc[4][4];
#pragma unroll
  for (int i = 0; i < 4; ++i)
#pragma unroll
    for (int j = 0; j < 4; ++j) acc[i][j] = (f32x4){0.f, 0.f, 0.f, 0.f};

  float4 ra[8], rb[8];
  load_tile(Abase, HD, ra);
  load_tile(Bbase, HD, rb);

  const int NK = HD / 64;
  for (int kt = 0; kt < NK; ++kt) {
    write_tile(sA, ra);
    write_tile(sB, rb);
    __syncthreads();
    if (kt + 1 < NK) {
      load_tile(Abase + (kt + 1) * 64, HD, ra);
      load_tile(Bbase + (kt + 1) * 64, HD, rb);
    }
    compute_tile(sA, sB, acc, wr, wc, l16, h16);
    __syncthreads();
  }

  const float th = thresh[l];
#pragma unroll
  for (int j = 0; j < 4; ++j) {
    int col = f0 + wc * 64 + j * 16 + l16;
    float bev = be[(size_t)l * FD + col];
#pragma unroll
    for (int i = 0; i < 4; ++i) {
      int rbase = m0 + wr * 64 + i * 16 + h16 * 4;
#pragma unroll
      for (int q = 0; q < 4; ++q) {
        float v = acc[i][j][q] + bev;
        float g = (v > th) ? v : 0.f;
        size_t idx = ((size_t)l * MT + rbase + q) * FD + col;
        feats[idx] = g;
        if (feats_bf) feats_bf[idx] = (unsigned short)f2bf1(g);
      }
    }
  }
}

// ---------------- enc8: dec8-skeleton encoder GEMM -------------------------
// A = res_bf[l] (M x K=1024), B = we_bf[l] (F x K), both K-major bf16.
// BM=256 BN=128 BK=64, 3 LDS buffers, depth-2, vmcnt(6), R9 frag pipeline.
#define DEC_ABUF 32768
#define DEC_BUFSZ 49152
__global__ __launch_bounds__(512, 2) void enc8(
    const unsigned short* __restrict__ resbf,
    const unsigned short* __restrict__ webf,
    const float* __restrict__ be, const float* __restrict__ thresh,
    float* __restrict__ feats, unsigned short* __restrict__ feats_bf) {
  __shared__ char lds[3 * DEC_BUFSZ];

  // XCD-chunk swizzle over 2048 blocks (8 XCDs x 256 chunks): XCD x = layer x.
  const int flat = (int)(blockIdx.x + 32 * blockIdx.y + 256 * blockIdx.z);
  const int nf = (flat & 7) * 256 + (flat >> 3);
  const int bx = nf & 31;          // f-tile 0..31
  const int by = (nf >> 5) & 7;    // m-tile 0..7
  const int l  = nf >> 8;          // layer 0..7

  const int m0 = by * 256;
  const int f0 = bx * 128;

  const int t = threadIdx.x;          // 0..511
  const int L = t & 63;
  const int w = t >> 6;               // 8 waves
  const int wm = w >> 1, wn = w & 1;  // 4M x 2N
  const int l16 = L & 15, h16 = L >> 4;

  const int rl   = (t >> 3) & 7;
  const int scol = (t & 7) ^ rl;            // pre-swizzled source 16B-slot
  const int rowl = t >> 3;                  // 0..63
  const unsigned short* Abase = resbf + (size_t)l * MT * HD;
  const unsigned short* Bbase = webf + (size_t)l * FD * HD;
  const size_t laneA = (size_t)(m0 + rowl) * HD + scol * 8;
  const size_t laneB = (size_t)(f0 + rowl) * HD + scol * 8;

  const int s0 = h16 ^ (l16 & 7);
  const int NT = HD / 64;             // 16

  f32x4 acc[4][4];
#pragma unroll
  for (int i = 0; i < 4; ++i)
#pragma unroll
    for (int j = 0; j < 4; ++j) acc[i][j] = (f32x4){0.f, 0.f, 0.f, 0.f};

  auto stage = [&](int bi, int tt) {
    const unsigned short* Ab = Abase + (size_t)tt * 64 + laneA;
    const unsigned short* Bb = Bbase + (size_t)tt * 64 + laneB;
    char* dA = lds + bi * DEC_BUFSZ + t * 16;
    char* dB = dA + DEC_ABUF;
#pragma unroll
    for (int i = 0; i < 4; ++i)
      gload16(Ab + (size_t)i * 64 * HD, dA + i * 8192);
#pragma unroll
    for (int i = 0; i < 2; ++i)
      gload16(Bb + (size_t)i * 64 * HD, dB + i * 8192);
  };

  auto rfrag = [&](int bi, int ks, short8* a, short8* b) {
    const char* cA = lds + bi * DEC_BUFSZ;
    const char* cB = cA + DEC_ABUF;
    const int sl = (s0 ^ (ks << 2)) << 4;
#pragma unroll
    for (int i = 0; i < 4; ++i) {
      int row = wm * 64 + i * 16 + l16;
      a[i] = *(const short8*)(cA + row * 128 + sl);
    }
#pragma unroll
    for (int j = 0; j < 4; ++j) {
      int col = wn * 64 + j * 16 + l16;
      b[j] = *(const short8*)(cB + col * 128 + sl);
    }
  };

  auto cluster = [&](const short8* a, const short8* b) {
    __builtin_amdgcn_s_setprio(1);
#pragma unroll
    for (int i = 0; i < 4; ++i)
#pragma unroll
      for (int j = 0; j < 4; ++j)
        acc[i][j] = __builtin_amdgcn_mfma_f32_16x16x32_bf16(a[i], b[j], acc[i][j], 0, 0, 0);
    __builtin_amdgcn_s_setprio(0);
  };

  stage(0, 0);
  stage(1, 1);
  asm volatile("s_waitcnt vmcnt(6)" ::: "memory");
  BAR();

  short8 aC[4], bC[4], aN[4], bN[4];
  rfrag(0, 0, aC, bC);

  int rd = 0;
  for (int tt = 0; tt < NT; ++tt) {
    int st = rd + 2;
    if (st >= 3) st -= 3;
    if (tt + 2 < NT) stage(st, tt + 2);
    rfrag(rd, 1, aN, bN);
    cluster(aC, bC);
    if (tt + 2 < NT) {
      asm volatile("s_waitcnt vmcnt(6)" ::: "memory");
    } else if (tt + 1 < NT) {
      asm volatile("s_waitcnt vmcnt(0)" ::: "memory");
    }
    BAR();
    int nrd = (rd + 1 == 3) ? 0 : rd + 1;
    if (tt + 1 < NT) rfrag(nrd, 0, aC, bC);
    cluster(aN, bN);
    rd = nrd;
  }

  const float th = thresh[l];
#pragma unroll
  for (int j = 0; j < 4; ++j) {
    int col = f0 + wn * 64 + j * 16 + l16;
    float bev = be[(size_t)l * FD + col];
#pragma unroll
    for (int i = 0; i < 4; ++i) {
      int rbase = m0 + wm * 64 + i * 16 + h16 * 4;
#pragma unroll
      for (int q = 0; q < 4; ++q) {
        float v = acc[i][j][q] + bev;
        float g = (v > th) ? v : 0.f;
        size_t idx = ((size_t)l * MT + rbase + q) * FD + col;
        feats[idx] = g;
        feats_bf[idx] = (unsigned short)f2bf1(g);
      }
    }
  }
}

// ---------------- Decoder: deep pipeline + frag software pipeline (R9) -----
__global__ __launch_bounds__(512, 2) void dec8(
    const unsigned short* __restrict__ featsbf,
    const unsigned short* __restrict__ wdbf,
    const float* __restrict__ bd, float* __restrict__ recon) {
  __shared__ char lds[3 * DEC_BUFSZ];   // 144 KB -> 1 block/CU

  const int flat = (int)(blockIdx.x + 8 * blockIdx.y + 64 * blockIdx.z);
  const int nf = (flat & 7) * 32 + (flat >> 3);
  const int bx = nf & 7;          // h-tile
  const int by = (nf >> 3) & 7;   // m-tile
  const int z  = nf >> 6;         // 0..3 -> lp pair (7-z, z)

  const int m0 = by * 256;
  const int h0 = bx * 128;

  const int t = threadIdx.x;          // 0..511
  const int L = t & 63;
  const int w = t >> 6;               // 8 waves
  const int wm = w >> 1, wn = w & 1;  // 4M x 2N
  const int l16 = L & 15, h16 = L >> 4;

  const int rl   = (t >> 3) & 7;
  const int scol = (t & 7) ^ rl;            // pre-swizzled source 16B-slot
  const int rowl = t >> 3;                  // 0..63
  const size_t laneA = (size_t)(m0 + rowl) * FD + scol * 8;
  const size_t laneB = (size_t)(h0 + rowl) * FD + scol * 8;

  const int s0 = h16 ^ (l16 & 7);

  for (int sub = 0; sub < 2; ++sub) {
    const int lp = sub ? z : 7 - z;
    const int NT = (lp + 1) * 64;

    f32x4 acc[4][4];
#pragma unroll
    for (int i = 0; i < 4; ++i)
#pragma unroll
      for (int j = 0; j < 4; ++j) acc[i][j] = (f32x4){0.f, 0.f, 0.f, 0.f};

    auto stage = [&](int bi, int tt) {
      int l = tt >> 6, kt = tt & 63;
      int p = l * LL - ((l * (l - 1)) >> 1) + (lp - l);
      const unsigned short* Ab = featsbf + (size_t)l * MT * FD + kt * 64 + laneA;
      const unsigned short* Bb = wdbf + (size_t)p * HD * FD + kt * 64 + laneB;
      char* dA = lds + bi * DEC_BUFSZ + t * 16;
      char* dB = dA + DEC_ABUF;
#pragma unroll
      for (int i = 0; i < 4; ++i)
        gload16(Ab + (size_t)i * 64 * FD, dA + i * 8192);
#pragma unroll
      for (int i = 0; i < 2; ++i)
        gload16(Bb + (size_t)i * 64 * FD, dB + i * 8192);
    };

    auto rfrag = [&](int bi, int ks, short8* a, short8* b) {
      const char* cA = lds + bi * DEC_BUFSZ;
      const char* cB = cA + DEC_ABUF;
      const int sl = (s0 ^ (ks << 2)) << 4;
#pragma unroll
      for (int i = 0; i < 4; ++i) {
        int row = wm * 64 + i * 16 + l16;
        a[i] = *(const short8*)(cA + row * 128 + sl);
      }
#pragma unroll
      for (int j = 0; j < 4; ++j) {
        int col = wn * 64 + j * 16 + l16;
        b[j] = *(const short8*)(cB + col * 128 + sl);
      }
    };

    auto cluster = [&](const short8* a, const short8* b) {
      __builtin_amdgcn_s_setprio(1);
#pragma unroll
      for (int i = 0; i < 4; ++i)
#pragma unroll
        for (int j = 0; j < 4; ++j)
          acc[i][j] = __builtin_amdgcn_mfma_f32_16x16x32_bf16(a[i], b[j], acc[i][j], 0, 0, 0);
      __builtin_amdgcn_s_setprio(0);
    };

    stage(0, 0);
    stage(1, 1);
    asm volatile("s_waitcnt vmcnt(6)" ::: "memory");
    BAR();

    short8 aC[4], bC[4], aN[4], bN[4];
    rfrag(0, 0, aC, bC);

    int rd = 0;
    for (int tt = 0; tt < NT; ++tt) {
      int st = rd + 2;
      if (st >= 3) st -= 3;
      if (tt + 2 < NT) stage(st, tt + 2);
      rfrag(rd, 1, aN, bN);
      cluster(aC, bC);
      if (tt + 2 < NT) {
        asm volatile("s_waitcnt vmcnt(6)" ::: "memory");
      } else if (tt + 1 < NT) {
        asm volatile("s_waitcnt vmcnt(0)" ::: "memory");
      }
      BAR();
      int nrd = (rd + 1 == 3) ? 0 : rd + 1;
      if (tt + 1 < NT) rfrag(nrd, 0, aC, bC);
      cluster(aN, bN);
      rd = nrd;
    }

#pragma unroll
    for (int j = 0; j < 4; ++j) {
      int col = h0 + wn * 64 + j * 16 + l16;
      float bsum = 0.f;
      for (int l = 0; l <= lp; ++l) {
        int p = l * LL - ((l * (l - 1)) >> 1) + (lp - l);
        bsum += bd[(size_t)p * HD + col];
      }
#pragma unroll
      for (int i = 0; i < 4; ++i) {
        int rbase = m0 + wm * 64 + i * 16 + h16 * 4;
#pragma unroll
        for (int q = 0; q < 4; ++q)
          recon[((size_t)lp * MT + rbase + q) * HD + col] = acc[i][j][q] + bsum;
      }
    }
  }
}

// ---------------- Fallback decoder (R2 2-phase, reg-staged) ----------------
template <bool ABF16>
__global__ __launch_bounds__(256, 2) void dec_kernel(
    const float* __restrict__ feats_f32, const unsigned short* __restrict__ feats_bf,
    const float* __restrict__ Wd, const float* __restrict__ bd,
    float* __restrict__ recon) {
  __shared__ char sA[128 * 64 * 2];
  __shared__ char sB[128 * 64 * 2];

  const int lp = (LL - 1) - (int)blockIdx.z;
  const int m0 = blockIdx.y * 128;
  const int h0 = blockIdx.x * 128;

  const int t = threadIdx.x;
  const int lane = t & 63, wave = t >> 6;
  const int wr = wave >> 1, wc = wave & 1;
  const int l16 = lane & 15, h16 = lane >> 4;

  f32x4 acc[4][4];
#pragma unroll
  for (int i = 0; i < 4; ++i)
#pragma unroll
    for (int j = 0; j < 4; ++j) acc[i][j] = (f32x4){0.f, 0.f, 0.f, 0.f};

  const int nit = (lp + 1) * (FD / 64);

  auto Abf = [&](int it) -> const unsigned short* {
    int l = it >> 6, kt = it & 63;
    return feats_bf + ((size_t)l * MT + m0) * FD + kt * 64;
  };
  auto Af = [&](int it) -> const float* {
    int l = it >> 6, kt = it & 63;
    return feats_f32 + ((size_t)l * MT + m0) * FD + kt * 64;
  };
  auto Bb = [&](int it) -> const float* {
    int l = it >> 6, kt = it & 63;
    int p = l * LL - l * (l - 1) / 2 + (lp - l);
    return Wd + ((size_t)p * HD + h0) * FD + kt * 64;
  };

  short8 rab[4];
  float4 raf[8];
  float4 rb[8];
  if constexpr (ABF16) load_tile_bf(Abf(0), FD, rab); else load_tile(Af(0), FD, raf);
  load_tile(Bb(0), FD, rb);

  for (int it = 0; it < nit; ++it) {
    if constexpr (ABF16) write_tile_bf(sA, rab); else write_tile(sA, raf);
    write_tile(sB, rb);
    __syncthreads();
    if (it + 1 < nit) {
      if constexpr (ABF16) load_tile_bf(Abf(it + 1), FD, rab);
      else                 load_tile(Af(it + 1), FD, raf);
      load_tile(Bb(it + 1), FD, rb);
    }
    compute_tile(sA, sB, acc, wr, wc, l16, h16);
    __syncthreads();
  }

#pragma unroll
  for (int j = 0; j < 4; ++j) {
    int col = h0 + wc * 64 + j * 16 + l16;
    float bsum = 0.f;
    for (int l = 0; l <= lp; ++l) {
      int p = l * LL - l * (l - 1) / 2 + (lp - l);
      bsum += bd[(size_t)p * HD + col];
    }
#pragma unroll
    for (int i = 0; i < 4; ++i) {
      int rbase = m0 + wr * 64 + i * 16 + h16 * 4;
#pragma unroll
      for (int q = 0; q < 4; ++q) {
        recon[((size_t)lp * MT + rbase + q) * HD + col] = acc[i][j][q] + bsum;
      }
    }
  }
}

extern "C" void kernel_launch(void* const* d_in, const int* in_sizes, int n_in,
                              void* d_out, int out_size, void* d_ws, size_t ws_size,
                              hipStream_t stream) {
  const float* res    = (const float*)d_in[0];
  const float* We     = (const float*)d_in[1];
  const float* be     = (const float*)d_in[2];
  const float* Wd     = (const float*)d_in[3];
  const float* bd     = (const float*)d_in[4];
  const float* thresh = (const float*)d_in[5];

  float* recon = (float*)d_out;                       // L*M*H
  float* feats = recon + (size_t)LL * MT * HD;        // L*M*F

  const size_t featsbf_b = (size_t)LL * MT * FD * 2;  // 128 MiB
  const size_t wdbf_b    = (size_t)36 * HD * FD * 2;  // 288 MiB
  const size_t resbf_b   = (size_t)LL * MT * HD * 2;  //  32 MiB
  const size_t webf_b    = (size_t)LL * FD * HD * 2;  //  64 MiB

  const bool use_bf   = ws_size >= featsbf_b;
  const bool use_full = ws_size >= featsbf_b + wdbf_b;
  const bool use_v3   = ws_size >= featsbf_b + wdbf_b + resbf_b + webf_b; // 512 MiB

  unsigned short* feats_bf = (unsigned short*)d_ws;
  unsigned short* wd_bf    = (unsigned short*)((char*)d_ws + featsbf_b);
  unsigned short* res_bf   = (unsigned short*)((char*)d_ws + featsbf_b + wdbf_b);
  unsigned short* we_bf    = (unsigned short*)((char*)d_ws + featsbf_b + wdbf_b + resbf_b);

  if (use_v3) {
    conv_kernel<<<dim3(2048), dim3(256), 0, stream>>>(res, We, Wd, res_bf, we_bf, wd_bf);
    enc8<<<dim3(32, 8, 8), dim3(512), 0, stream>>>(res_bf, we_bf, be, thresh,
                                                   feats, feats_bf);
    dec8<<<dim3(8, 8, 4), dim3(512), 0, stream>>>(feats_bf, wd_bf, bd, recon);
  } else if (use_full) {
    enc_kernel<<<dim3(32, 16, LL + 2), dim3(256), 0, stream>>>(
        res, We, be, thresh, feats, feats_bf, Wd, wd_bf, 2);
    dec8<<<dim3(8, 8, 4), dim3(512), 0, stream>>>(feats_bf, wd_bf, bd, recon);
  } else if (use_bf) {
    enc_kernel<<<dim3(32, 16, LL), dim3(256), 0, stream>>>(
        res, We, be, thresh, feats, feats_bf, nullptr, nullptr, 0);
    dec_kernel<true><<<dim3(8, 16, LL), dim3(256), 0, stream>>>(
        feats, feats_bf, Wd, bd, recon);
  } else {
    enc_kernel<<<dim3(32, 16, LL), dim3(256), 0, stream>>>(
        res, We, be, thresh, feats, nullptr, nullptr, nullptr, 0);
    dec_kernel<false><<<dim3(8, 16, LL), dim3(256), 0, stream>>>(
        feats, nullptr, Wd, bd, recon);
  }
}